// Round 5
// baseline (216.723 us; speedup 1.0000x reference)
//
#include <hip/hip_runtime.h>
#include <hip/hip_bf16.h>

#define N_NODES 50000
#define N_EDGES 800000
#define N_IN    256
#define N_H     64
#define NB      125    // buckets per graph
#define RPB     400    // rows per bucket (NB*RPB == N_NODES)
#define BCAP    8192   // bucket capacity (mean 6400)
#define EPT     8      // edges per thread in k_bin
#define BIN_BLK 2048   // edges per k_bin block
#define GSTRIDE 264    // u16 per WT row (256 + 8 pad)

typedef short short8 __attribute__((ext_vector_type(8)));
typedef float f32x4  __attribute__((ext_vector_type(4)));

__device__ inline short f2bf(float f) {
    __bf16 h = (__bf16)f;
    return (short)__builtin_bit_cast(unsigned short, h);
}
__device__ inline float bflo(unsigned int q) { return __uint_as_float(q << 16); }
__device__ inline float bfhi(unsigned int q) { return __uint_as_float(q & 0xFFFF0000u); }

// ---------------- phase 1: bin edges by row range ----------------

__global__ __launch_bounds__(256) void k_bin(
    const int* __restrict__ adj_rows, const int* __restrict__ adj_cols,
    const float* __restrict__ adj_w,
    const int* __restrict__ diff_rows, const int* __restrict__ diff_cols,
    const float* __restrict__ diff_w,
    int* __restrict__ gcnt, int2* __restrict__ bin) {

    int g = blockIdx.y;
    const int*   rows = g ? diff_rows : adj_rows;
    const int*   cols = g ? diff_cols : adj_cols;
    const float* ww   = g ? diff_w    : adj_w;
    int base_e = blockIdx.x * BIN_BLK;
    int t = threadIdx.x;

    __shared__ int lcnt[NB];
    __shared__ int lbase[NB];
    for (int i = t; i < NB; i += 256) lcnt[i] = 0;
    __syncthreads();

    int lpos[EPT];
    int bkt[EPT];
    #pragma unroll
    for (int e = 0; e < EPT; ++e) {
        int idx = base_e + e * 256 + t;
        if (idx < N_EDGES) {
            int r = rows[idx];
            int b = r / RPB;
            bkt[e] = b;
            lpos[e] = atomicAdd(&lcnt[b], 1);
        } else bkt[e] = -1;
    }
    __syncthreads();
    for (int i = t; i < NB; i += 256) lbase[i] = atomicAdd(&gcnt[g * NB + i], lcnt[i]);
    __syncthreads();

    #pragma unroll
    for (int e = 0; e < EPT; ++e) {
        int idx = base_e + e * 256 + t;
        if (idx < N_EDGES) {
            unsigned int r = (unsigned int)rows[idx];
            unsigned int c = (unsigned int)cols[idx];
            int b = bkt[e];
            int2 m;
            m.x = (int)((r << 16) | c);
            m.y = __float_as_int(ww[idx]);
            bin[((size_t)(g * NB + b)) * BCAP + lbase[b] + lpos[e]] = m;
        }
    }
}

// ---------------- phase 2: per-bucket CSR build ----------------

__global__ __launch_bounds__(256) void k_build(
    const int* __restrict__ gcnt, const int2* __restrict__ bin,
    int2* __restrict__ csr, int* __restrict__ row_ptr) {

    int g = blockIdx.y, b = blockIdx.x, t = threadIdx.x;
    __shared__ int hist[512];
    __shared__ int s2[256];
    __shared__ int sbase;

    for (int i = t; i < 512; i += 256) hist[i] = 0;
    __syncthreads();

    int cnt = gcnt[g * NB + b];
    const int2* be = bin + ((size_t)(g * NB + b)) * BCAP;
    int r0 = b * RPB;

    for (int i = t; i < cnt; i += 256) {
        unsigned int rc = (unsigned int)be[i].x;
        atomicAdd(&hist[(rc >> 16) - r0], 1);
    }
    __syncthreads();

    if (t == 0) {
        int s = 0;
        for (int i = 0; i < b; ++i) s += gcnt[g * NB + i];
        sbase = s;
    }

    int v0 = hist[2 * t], v1 = hist[2 * t + 1];
    int local = v0 + v1;
    s2[t] = local;
    __syncthreads();
    for (int off = 1; off < 256; off <<= 1) {
        int v = (t >= off) ? s2[t - off] : 0;
        __syncthreads();
        s2[t] += v;
        __syncthreads();
    }
    int e0 = sbase + (s2[t] - local);
    int e1 = e0 + v0;

    int* rp = row_ptr + g * (N_NODES + 1);
    if (2 * t < RPB)     rp[r0 + 2 * t]     = e0;
    if (2 * t + 1 < RPB) rp[r0 + 2 * t + 1] = e1;
    __syncthreads();
    hist[2 * t] = e0;
    hist[2 * t + 1] = e1;
    __syncthreads();

    int2* cg = csr + (size_t)g * N_EDGES;
    for (int i = t; i < cnt; i += 256) {
        int2 m = be[i];
        unsigned int rc = (unsigned int)m.x;
        int lr = (int)(rc >> 16) - r0;
        int pos = atomicAdd(&hist[lr], 1);
        int2 o;
        o.x = (int)(rc & 0xFFFFu);
        o.y = m.y;
        cg[pos] = o;
    }
    if (b == NB - 1 && t == 0) rp[N_NODES] = N_EDGES;
}

// ---------------- prep: padded bf16 W^T tables in global ----------------

__global__ __launch_bounds__(256) void k_wt(const float* __restrict__ W1,
                                            const float* __restrict__ W2,
                                            unsigned short* __restrict__ WTg) {
    int g = blockIdx.x;
    const float* W = g ? W2 : W1;
    unsigned short* o = WTg + (size_t)g * 64 * GSTRIDE;
    for (int i = threadIdx.x; i < N_IN * N_H; i += 256) {
        int k = i >> 6, c = i & 63;
        o[c * GSTRIDE + k] = (unsigned short)f2bf(W[i]);
    }
}

// ---------------- GEMM: T[n][128] (bf16); block does both col-halves ----------------

__global__ __launch_bounds__(512, 6) void k_gemm(
    const float* __restrict__ X0, const float* __restrict__ X1,
    const float* __restrict__ X2, const float* __restrict__ X3,
    const unsigned short* __restrict__ WTg,
    unsigned short* __restrict__ Tadj, unsigned short* __restrict__ Tdiff) {

    int g = blockIdx.y;
    const float* Xa = g ? X1 : X0;     // -> cols 0..63
    const float* Xb = g ? X3 : X2;     // -> cols 64..127
    unsigned short* T = g ? Tdiff : Tadj;
    const unsigned short* src = WTg + (size_t)g * 64 * GSTRIDE;

    // linear identity memcpy staging: conflict-free ds_write_b128
    __shared__ __align__(16) unsigned short WT[64 * GSTRIDE];   // 33792 B = 2112 x 16B
    {
        const uint4* s4 = (const uint4*)src;
        uint4* d4 = (uint4*)WT;
        int t = threadIdx.x;
        #pragma unroll
        for (int j = 0; j < 4; ++j) d4[t + 512 * j] = s4[t + 512 * j];
        if (t < 64) d4[2048 + t] = s4[2048 + t];
    }
    __syncthreads();

    int wid  = threadIdx.x >> 6;
    int lane = threadIdx.x & 63;
    int rb = blockIdx.x * 128 + wid * 16;
    if (rb >= N_NODES) return;

    int arow = rb + (lane & 15);
    int kg   = lane >> 4;
    const float* apa = Xa + (size_t)arow * N_IN + kg * 8;
    const float* apb = Xb + (size_t)arow * N_IN + kg * 8;

    f32x4 acc[2][4];
    #pragma unroll
    for (int s = 0; s < 2; ++s)
        #pragma unroll
        for (int ct = 0; ct < 4; ++ct) acc[s][ct] = (f32x4){0.f, 0.f, 0.f, 0.f};

    for (int kt = 0; kt < 8; ++kt) {
        const float4* pa = reinterpret_cast<const float4*>(apa + kt * 32);
        const float4* pb = reinterpret_cast<const float4*>(apb + kt * 32);
        float4 a0 = pa[0];
        float4 a1 = pa[1];
        float4 c0 = pb[0];
        float4 c1 = pb[1];
        short8 afa, afb;
        afa[0] = f2bf(a0.x); afa[1] = f2bf(a0.y); afa[2] = f2bf(a0.z); afa[3] = f2bf(a0.w);
        afa[4] = f2bf(a1.x); afa[5] = f2bf(a1.y); afa[6] = f2bf(a1.z); afa[7] = f2bf(a1.w);
        afb[0] = f2bf(c0.x); afb[1] = f2bf(c0.y); afb[2] = f2bf(c0.z); afb[3] = f2bf(c0.w);
        afb[4] = f2bf(c1.x); afb[5] = f2bf(c1.y); afb[6] = f2bf(c1.z); afb[7] = f2bf(c1.w);
        #pragma unroll
        for (int ct = 0; ct < 4; ++ct) {
            const unsigned short* wp = &WT[(ct * 16 + (lane & 15)) * GSTRIDE + kt * 32 + kg * 8];
            short8 bfr = *reinterpret_cast<const short8*>(wp);
            acc[0][ct] = __builtin_amdgcn_mfma_f32_16x16x32_bf16(afa, bfr, acc[0][ct], 0, 0, 0);
            acc[1][ct] = __builtin_amdgcn_mfma_f32_16x16x32_bf16(afb, bfr, acc[1][ct], 0, 0, 0);
        }
    }

    // C/D layout: D[row=(lane>>4)*4+r][col=lane&15]
    int rgrp = lane >> 4;
    #pragma unroll
    for (int ct = 0; ct < 4; ++ct) {
        int col = ct * 16 + (lane & 15);
        #pragma unroll
        for (int r = 0; r < 4; ++r) {
            int row = rb + rgrp * 4 + r;
            if (row < N_NODES) {
                T[(size_t)row * 128 + col]      = (unsigned short)f2bf(acc[0][ct][r]);
                T[(size_t)row * 128 + 64 + col] = (unsigned short)f2bf(acc[1][ct][r]);
            }
        }
    }
}

// ---------------- Aggregate (gather) + bias + PReLU ----------------

__global__ __launch_bounds__(256) void k_agg(
    const int* __restrict__ row_ptr, const int2* __restrict__ csr,
    const unsigned int* __restrict__ Tadj, const unsigned int* __restrict__ Tdiff,
    const float* __restrict__ b1, const float* __restrict__ a1,
    const float* __restrict__ b2, const float* __restrict__ a2,
    float* __restrict__ out) {

    int wid  = threadIdx.x >> 6;
    int lane = threadIdx.x & 63;
    int node = blockIdx.x * 4 + wid;
    int g    = blockIdx.y;

    const int* rp = row_ptr + g * (N_NODES + 1);
    const int2* el = csr + (size_t)g * N_EDGES;
    const unsigned int* Tu = g ? Tdiff : Tadj;

    int e  = rp[node];
    int e1 = rp[node + 1];
    float ax = 0.f, ay = 0.f;

    for (; e + 4 <= e1; e += 4) {
        int2 m0 = el[e + 0], m1 = el[e + 1], m2 = el[e + 2], m3 = el[e + 3];
        unsigned int q0 = Tu[(size_t)m0.x * 64 + lane];
        unsigned int q1 = Tu[(size_t)m1.x * 64 + lane];
        unsigned int q2 = Tu[(size_t)m2.x * 64 + lane];
        unsigned int q3 = Tu[(size_t)m3.x * 64 + lane];
        float w0 = __int_as_float(m0.y), w1 = __int_as_float(m1.y);
        float w2 = __int_as_float(m2.y), w3 = __int_as_float(m3.y);
        ax += w0 * bflo(q0); ay += w0 * bfhi(q0);
        ax += w1 * bflo(q1); ay += w1 * bfhi(q1);
        ax += w2 * bflo(q2); ay += w2 * bfhi(q2);
        ax += w3 * bflo(q3); ay += w3 * bfhi(q3);
    }
    for (; e < e1; ++e) {
        int2 m = el[e];
        unsigned int q = Tu[(size_t)m.x * 64 + lane];
        float w = __int_as_float(m.y);
        ax += w * bflo(q); ay += w * bfhi(q);
    }

    const float* bias = g ? b2 : b1;
    float slope = g ? a2[0] : a1[0];
    int f = 2 * lane;
    size_t base;
    int fo;
    if (lane < 32) { base = g ? (size_t)3200000 : (size_t)0;       fo = f; }
    else           { base = g ? (size_t)9600000 : (size_t)6400000; fo = f - 64; }
    float v0 = ax + bias[fo];
    float v1 = ay + bias[fo + 1];
    v0 = (v0 >= 0.f) ? v0 : slope * v0;
    v1 = (v1 >= 0.f) ? v1 : slope * v1;
    float2 res; res.x = v0; res.y = v1;
    *reinterpret_cast<float2*>(out + base + (size_t)node * 64 + fo) = res;
}

// ---------------- launch ----------------

extern "C" void kernel_launch(void* const* d_in, const int* in_sizes, int n_in,
                              void* d_out, int out_size, void* d_ws, size_t ws_size,
                              hipStream_t stream) {
    const float* bf_      = (const float*)d_in[0];
    const float* bl_      = (const float*)d_in[1];
    const float* shuf_fts = (const float*)d_in[2];
    const float* shuf_fls = (const float*)d_in[3];
    const int*   adj_rows = (const int*)d_in[4];
    const int*   adj_cols = (const int*)d_in[5];
    const float* adj_w    = (const float*)d_in[6];
    const int*   diff_rows= (const int*)d_in[7];
    const int*   diff_cols= (const int*)d_in[8];
    const float* diff_w   = (const float*)d_in[9];
    const float* W1       = (const float*)d_in[10];
    const float* b1       = (const float*)d_in[11];
    const float* a1       = (const float*)d_in[12];
    const float* W2       = (const float*)d_in[13];
    const float* b2       = (const float*)d_in[14];
    const float* a2       = (const float*)d_in[15];
    float* out = (float*)d_out;

    char* ws = (char*)d_ws;
    unsigned short* Tadj  = (unsigned short*)(ws);                         // 12.8 MB
    unsigned short* Tdiff = (unsigned short*)(ws + 12800000);              // 12.8 MB
    int2* csr             = (int2*)(ws + 25600000);                        // 12.8 MB
    int*  row_ptr         = (int*)(ws + 38400000);                         // 400 KB
    int*  gcnt            = (int*)(ws + 38801024);                         // 250 ints
    unsigned short* WTg   = (unsigned short*)(ws + 38803072);              // 67584 B

    // bin buckets live in d_out (16.4 MB <= 51.2 MB), dead before k_agg writes output
    int2* bin = (int2*)d_out;

    hipMemsetAsync(gcnt, 0, 2 * NB * sizeof(int), stream);

    k_bin<<<dim3((N_EDGES + BIN_BLK - 1) / BIN_BLK, 2), dim3(256), 0, stream>>>(
        adj_rows, adj_cols, adj_w, diff_rows, diff_cols, diff_w, gcnt, bin);
    k_wt<<<dim3(2), dim3(256), 0, stream>>>(W1, W2, WTg);
    k_build<<<dim3(NB, 2), dim3(256), 0, stream>>>(gcnt, bin, csr, row_ptr);

    k_gemm<<<dim3((N_NODES + 127) / 128, 2), dim3(512), 0, stream>>>(
        bf_, bl_, shuf_fts, shuf_fls, WTg, Tadj, Tdiff);

    k_agg<<<dim3(N_NODES / 4, 2), dim3(256), 0, stream>>>(
        row_ptr, csr, (const unsigned int*)Tadj, (const unsigned int*)Tdiff,
        b1, a1, b2, a2, out);
}

// Round 6
// 209.487 us; speedup vs baseline: 1.0345x; 1.0345x over previous
//
#include <hip/hip_runtime.h>
#include <hip/hip_bf16.h>

#define N_NODES 50000
#define N_EDGES 800000
#define N_IN    256
#define N_H     64
#define NB      125    // buckets per graph
#define RPB     400    // rows per bucket (NB*RPB == N_NODES)
#define BCAP    8192   // bucket capacity (mean 6400)
#define EPT     8      // edges per thread in k_bin
#define BIN_BLK 2048   // edges per k_bin block
#define GSTRIDE 264    // u16 per WT row (256 + 8 pad)

typedef short short8 __attribute__((ext_vector_type(8)));
typedef float f32x4  __attribute__((ext_vector_type(4)));

__device__ inline short f2bf(float f) {
    __bf16 h = (__bf16)f;
    return (short)__builtin_bit_cast(unsigned short, h);
}
__device__ inline float bflo(unsigned int q) { return __uint_as_float(q << 16); }
__device__ inline float bfhi(unsigned int q) { return __uint_as_float(q & 0xFFFF0000u); }

// ---------------- phase 1: bin edges by row range ----------------

__global__ __launch_bounds__(256) void k_bin(
    const int* __restrict__ adj_rows, const int* __restrict__ adj_cols,
    const float* __restrict__ adj_w,
    const int* __restrict__ diff_rows, const int* __restrict__ diff_cols,
    const float* __restrict__ diff_w,
    int* __restrict__ gcnt, int2* __restrict__ bin) {

    int g = blockIdx.y;
    const int*   rows = g ? diff_rows : adj_rows;
    const int*   cols = g ? diff_cols : adj_cols;
    const float* ww   = g ? diff_w    : adj_w;
    int base_e = blockIdx.x * BIN_BLK;
    int t = threadIdx.x;

    __shared__ int lcnt[NB];
    __shared__ int lbase[NB];
    for (int i = t; i < NB; i += 256) lcnt[i] = 0;
    __syncthreads();

    int lpos[EPT];
    int bkt[EPT];
    #pragma unroll
    for (int e = 0; e < EPT; ++e) {
        int idx = base_e + e * 256 + t;
        if (idx < N_EDGES) {
            int r = rows[idx];
            int b = r / RPB;
            bkt[e] = b;
            lpos[e] = atomicAdd(&lcnt[b], 1);
        } else bkt[e] = -1;
    }
    __syncthreads();
    for (int i = t; i < NB; i += 256) lbase[i] = atomicAdd(&gcnt[g * NB + i], lcnt[i]);
    __syncthreads();

    #pragma unroll
    for (int e = 0; e < EPT; ++e) {
        int idx = base_e + e * 256 + t;
        if (idx < N_EDGES) {
            unsigned int r = (unsigned int)rows[idx];
            unsigned int c = (unsigned int)cols[idx];
            int b = bkt[e];
            int2 m;
            m.x = (int)((r << 16) | c);
            m.y = __float_as_int(ww[idx]);
            bin[((size_t)(g * NB + b)) * BCAP + lbase[b] + lpos[e]] = m;
        }
    }
}

// ---------------- phase 2: per-bucket CSR build ----------------

__global__ __launch_bounds__(256) void k_build(
    const int* __restrict__ gcnt, const int2* __restrict__ bin,
    int2* __restrict__ csr, int* __restrict__ row_ptr) {

    int g = blockIdx.y, b = blockIdx.x, t = threadIdx.x;
    __shared__ int hist[512];
    __shared__ int s2[256];
    __shared__ int sbase;

    for (int i = t; i < 512; i += 256) hist[i] = 0;
    __syncthreads();

    int cnt = gcnt[g * NB + b];
    const int2* be = bin + ((size_t)(g * NB + b)) * BCAP;
    int r0 = b * RPB;

    for (int i = t; i < cnt; i += 256) {
        unsigned int rc = (unsigned int)be[i].x;
        atomicAdd(&hist[(rc >> 16) - r0], 1);
    }
    __syncthreads();

    if (t == 0) {
        int s = 0;
        for (int i = 0; i < b; ++i) s += gcnt[g * NB + i];
        sbase = s;
    }

    int v0 = hist[2 * t], v1 = hist[2 * t + 1];
    int local = v0 + v1;
    s2[t] = local;
    __syncthreads();
    for (int off = 1; off < 256; off <<= 1) {
        int v = (t >= off) ? s2[t - off] : 0;
        __syncthreads();
        s2[t] += v;
        __syncthreads();
    }
    int e0 = sbase + (s2[t] - local);
    int e1 = e0 + v0;

    int* rp = row_ptr + g * (N_NODES + 1);
    if (2 * t < RPB)     rp[r0 + 2 * t]     = e0;
    if (2 * t + 1 < RPB) rp[r0 + 2 * t + 1] = e1;
    __syncthreads();
    hist[2 * t] = e0;
    hist[2 * t + 1] = e1;
    __syncthreads();

    int2* cg = csr + (size_t)g * N_EDGES;
    for (int i = t; i < cnt; i += 256) {
        int2 m = be[i];
        unsigned int rc = (unsigned int)m.x;
        int lr = (int)(rc >> 16) - r0;
        int pos = atomicAdd(&hist[lr], 1);
        int2 o;
        o.x = (int)(rc & 0xFFFFu);
        o.y = m.y;
        cg[pos] = o;
    }
    if (b == NB - 1 && t == 0) rp[N_NODES] = N_EDGES;
}

// ---------------- prep: padded bf16 W^T tables in global ----------------

__global__ __launch_bounds__(256) void k_wt(const float* __restrict__ W1,
                                            const float* __restrict__ W2,
                                            unsigned short* __restrict__ WTg) {
    int g = blockIdx.x;
    const float* W = g ? W2 : W1;
    unsigned short* o = WTg + (size_t)g * 64 * GSTRIDE;
    for (int i = threadIdx.x; i < N_IN * N_H; i += 256) {
        int k = i >> 6, c = i & 63;
        o[c * GSTRIDE + k] = (unsigned short)f2bf(W[i]);
    }
}

// ---------------- GEMM: T[n][128] (bf16); 8 waves: even->cols 0..63, odd->64..127 ----------------

__global__ __launch_bounds__(512, 4) void k_gemm(
    const float* __restrict__ X0, const float* __restrict__ X1,
    const float* __restrict__ X2, const float* __restrict__ X3,
    const unsigned short* __restrict__ WTg,
    unsigned short* __restrict__ Tadj, unsigned short* __restrict__ Tdiff) {

    int g = blockIdx.y;
    unsigned short* T = g ? Tdiff : Tadj;
    const unsigned short* src = WTg + (size_t)g * 64 * GSTRIDE;

    // linear identity memcpy staging: conflict-free ds_write_b128
    __shared__ __align__(16) unsigned short WT[64 * GSTRIDE];   // 33792 B = 2112 x 16B
    {
        const uint4* s4 = (const uint4*)src;
        uint4* d4 = (uint4*)WT;
        int t = threadIdx.x;
        #pragma unroll
        for (int j = 0; j < 3; ++j) d4[t + 512 * j] = s4[t + 512 * j];
        d4[t + 1536] = s4[t + 1536];
        if (t < 64) d4[2048 + t] = s4[2048 + t];
    }
    __syncthreads();

    int wid  = threadIdx.x >> 6;
    int lane = threadIdx.x & 63;
    int s    = wid & 1;                            // stream: 0 -> cols 0..63, 1 -> cols 64..127
    int rb   = blockIdx.x * 64 + (wid >> 1) * 16;
    if (rb >= N_NODES) return;

    const float* X = s ? (g ? X3 : X2) : (g ? X1 : X0);
    int coloff = s * 64;

    int arow = rb + (lane & 15);
    if (arow >= N_NODES) arow = N_NODES - 1;       // clamp (stores guarded)
    int kg   = lane >> 4;
    const float4* p = reinterpret_cast<const float4*>(X + (size_t)arow * N_IN) + kg * 2;

    // hoist the whole 16-row x 256-col A panel: 16 independent loads in flight
    float4 rx[16];
    #pragma unroll
    for (int kt = 0; kt < 8; ++kt) {
        rx[2 * kt]     = p[kt * 8];
        rx[2 * kt + 1] = p[kt * 8 + 1];
    }

    f32x4 acc[4];
    #pragma unroll
    for (int ct = 0; ct < 4; ++ct) acc[ct] = (f32x4){0.f, 0.f, 0.f, 0.f};

    #pragma unroll
    for (int kt = 0; kt < 8; ++kt) {
        float4 a0 = rx[2 * kt];
        float4 a1 = rx[2 * kt + 1];
        short8 af;
        af[0] = f2bf(a0.x); af[1] = f2bf(a0.y); af[2] = f2bf(a0.z); af[3] = f2bf(a0.w);
        af[4] = f2bf(a1.x); af[5] = f2bf(a1.y); af[6] = f2bf(a1.z); af[7] = f2bf(a1.w);
        #pragma unroll
        for (int ct = 0; ct < 4; ++ct) {
            const unsigned short* wp = &WT[(ct * 16 + (lane & 15)) * GSTRIDE + kt * 32 + kg * 8];
            short8 bfr = *reinterpret_cast<const short8*>(wp);
            acc[ct] = __builtin_amdgcn_mfma_f32_16x16x32_bf16(af, bfr, acc[ct], 0, 0, 0);
        }
    }

    // C/D layout: D[row=(lane>>4)*4+r][col=lane&15]
    int rgrp = lane >> 4;
    #pragma unroll
    for (int ct = 0; ct < 4; ++ct) {
        int col = coloff + ct * 16 + (lane & 15);
        #pragma unroll
        for (int r = 0; r < 4; ++r) {
            int row = rb + rgrp * 4 + r;
            if (row < N_NODES)
                T[(size_t)row * 128 + col] = (unsigned short)f2bf(acc[ct][r]);
        }
    }
}

// ---------------- Aggregate (gather) + bias + PReLU ----------------

__global__ __launch_bounds__(256) void k_agg(
    const int* __restrict__ row_ptr, const int2* __restrict__ csr,
    const unsigned int* __restrict__ Tadj, const unsigned int* __restrict__ Tdiff,
    const float* __restrict__ b1, const float* __restrict__ a1,
    const float* __restrict__ b2, const float* __restrict__ a2,
    float* __restrict__ out) {

    int wid  = threadIdx.x >> 6;
    int lane = threadIdx.x & 63;
    int node = blockIdx.x * 4 + wid;
    int g    = blockIdx.y;

    const int* rp = row_ptr + g * (N_NODES + 1);
    const int2* el = csr + (size_t)g * N_EDGES;
    const unsigned int* Tu = g ? Tdiff : Tadj;

    int e  = rp[node];
    int e1 = rp[node + 1];
    float ax = 0.f, ay = 0.f;

    for (; e + 4 <= e1; e += 4) {
        int2 m0 = el[e + 0], m1 = el[e + 1], m2 = el[e + 2], m3 = el[e + 3];
        unsigned int q0 = Tu[(size_t)m0.x * 64 + lane];
        unsigned int q1 = Tu[(size_t)m1.x * 64 + lane];
        unsigned int q2 = Tu[(size_t)m2.x * 64 + lane];
        unsigned int q3 = Tu[(size_t)m3.x * 64 + lane];
        float w0 = __int_as_float(m0.y), w1 = __int_as_float(m1.y);
        float w2 = __int_as_float(m2.y), w3 = __int_as_float(m3.y);
        ax += w0 * bflo(q0); ay += w0 * bfhi(q0);
        ax += w1 * bflo(q1); ay += w1 * bfhi(q1);
        ax += w2 * bflo(q2); ay += w2 * bfhi(q2);
        ax += w3 * bflo(q3); ay += w3 * bfhi(q3);
    }
    for (; e < e1; ++e) {
        int2 m = el[e];
        unsigned int q = Tu[(size_t)m.x * 64 + lane];
        float w = __int_as_float(m.y);
        ax += w * bflo(q); ay += w * bfhi(q);
    }

    const float* bias = g ? b2 : b1;
    float slope = g ? a2[0] : a1[0];
    int f = 2 * lane;
    size_t base;
    int fo;
    if (lane < 32) { base = g ? (size_t)3200000 : (size_t)0;       fo = f; }
    else           { base = g ? (size_t)9600000 : (size_t)6400000; fo = f - 64; }
    float v0 = ax + bias[fo];
    float v1 = ay + bias[fo + 1];
    v0 = (v0 >= 0.f) ? v0 : slope * v0;
    v1 = (v1 >= 0.f) ? v1 : slope * v1;
    float2 res; res.x = v0; res.y = v1;
    *reinterpret_cast<float2*>(out + base + (size_t)node * 64 + fo) = res;
}

// ---------------- launch ----------------

extern "C" void kernel_launch(void* const* d_in, const int* in_sizes, int n_in,
                              void* d_out, int out_size, void* d_ws, size_t ws_size,
                              hipStream_t stream) {
    const float* bf_      = (const float*)d_in[0];
    const float* bl_      = (const float*)d_in[1];
    const float* shuf_fts = (const float*)d_in[2];
    const float* shuf_fls = (const float*)d_in[3];
    const int*   adj_rows = (const int*)d_in[4];
    const int*   adj_cols = (const int*)d_in[5];
    const float* adj_w    = (const float*)d_in[6];
    const int*   diff_rows= (const int*)d_in[7];
    const int*   diff_cols= (const int*)d_in[8];
    const float* diff_w   = (const float*)d_in[9];
    const float* W1       = (const float*)d_in[10];
    const float* b1       = (const float*)d_in[11];
    const float* a1       = (const float*)d_in[12];
    const float* W2       = (const float*)d_in[13];
    const float* b2       = (const float*)d_in[14];
    const float* a2       = (const float*)d_in[15];
    float* out = (float*)d_out;

    char* ws = (char*)d_ws;
    unsigned short* Tadj  = (unsigned short*)(ws);                         // 12.8 MB
    unsigned short* Tdiff = (unsigned short*)(ws + 12800000);              // 12.8 MB
    int2* csr             = (int2*)(ws + 25600000);                        // 12.8 MB
    int*  row_ptr         = (int*)(ws + 38400000);                         // 400 KB
    int*  gcnt            = (int*)(ws + 38801024);                         // 250 ints
    unsigned short* WTg   = (unsigned short*)(ws + 38803072);              // 67584 B

    // bin buckets live in d_out (16.4 MB <= 51.2 MB), dead before k_agg writes output
    int2* bin = (int2*)d_out;

    hipMemsetAsync(gcnt, 0, 2 * NB * sizeof(int), stream);

    k_bin<<<dim3((N_EDGES + BIN_BLK - 1) / BIN_BLK, 2), dim3(256), 0, stream>>>(
        adj_rows, adj_cols, adj_w, diff_rows, diff_cols, diff_w, gcnt, bin);
    k_wt<<<dim3(2), dim3(256), 0, stream>>>(W1, W2, WTg);
    k_build<<<dim3(NB, 2), dim3(256), 0, stream>>>(gcnt, bin, csr, row_ptr);

    k_gemm<<<dim3((N_NODES + 63) / 64, 2), dim3(512), 0, stream>>>(
        bf_, bl_, shuf_fts, shuf_fls, WTg, Tadj, Tdiff);

    k_agg<<<dim3(N_NODES / 4, 2), dim3(256), 0, stream>>>(
        row_ptr, csr, (const unsigned int*)Tadj, (const unsigned int*)Tdiff,
        b1, a1, b2, a2, out);
}